// Round 3
// baseline (1201.098 us; speedup 1.0000x reference)
//
#include <hip/hip_runtime.h>

// Problem constants (from reference)
#define H_DIM 2048
#define E_DIM 8
#define T_DIM 2048
#define F_DIM 4096                    // INTER*2
#define ROWS (E_DIM * H_DIM)          // 16384 (e,h) rows of W
#define A_BLOCKS 8                    // 2 h-blocks (1024 h) x 4 t-chunks (512 t)
#define TCHUNK 512
#define TCHUNKS 4
#define RS_BLOCKS (ROWS / 4)          // 4096 rowsum blocks, 1 wave/row
#define TOTAL_BLOCKS (A_BLOCKS + RS_BLOCKS)
#define CTR_OFF (ROWS + TCHUNKS * ROWS)   // float index of arrival counter

typedef float f32x4 __attribute__((ext_vector_type(4)));

// ws layout (floats): [0,ROWS)=Bsum  [ROWS, ROWS+4*ROWS)=Ap partials
//                     [CTR_OFF] = arrival counter (int, memset to 0 pre-launch)

__global__ __launch_bounds__(256) void fused_all(
    const float* __restrict__ hidden,   // [T, H]
    const float* __restrict__ W,        // [E, H, F]
    const float* __restrict__ mask,     // [E, T]
    float* __restrict__ ws,
    float* __restrict__ out) {
  float* Bsum = ws;
  float* Ap   = ws + ROWS;
  int* counter = (int*)(ws + CTR_OFF);

  __shared__ float m_lds[E_DIM][TCHUNK];   // 16 KB, A-path only
  __shared__ float red[4];
  __shared__ int is_last;

  int bid = blockIdx.x;
  int tid = threadIdx.x;

  if (bid < A_BLOCKS) {
    // --- A[e,h] partials: Ap[tc][e,h] = sum_{t in chunk} mask[e,t]*hidden[t,h]
    int hb = bid & 1;                // 2 h-blocks of 1024 columns
    int tc = bid >> 1;               // 4 t-chunks of 512
    int t0 = tc * TCHUNK;
    int h4 = hb * 1024 + tid * 4;    // each thread owns 4 consecutive h

    #pragma unroll
    for (int i = 0; i < (E_DIM * TCHUNK) / 256; ++i) {   // 16 iters
      int idx = i * 256 + tid;
      int e = idx >> 9, tt = idx & 511;
      m_lds[e][tt] = mask[e * T_DIM + t0 + tt];
    }
    __syncthreads();

    f32x4 acc[E_DIM];
    #pragma unroll
    for (int e = 0; e < E_DIM; ++e) acc[e] = (f32x4)0.f;
    #pragma unroll 2
    for (int t = 0; t < TCHUNK; ++t) {
      f32x4 hv = *(const f32x4*)(hidden + (size_t)(t0 + t) * H_DIM + h4);
      #pragma unroll
      for (int e = 0; e < E_DIM; ++e)
        acc[e] += hv * m_lds[e][t];          // wave-uniform LDS broadcast
    }
    #pragma unroll
    for (int e = 0; e < E_DIM; ++e)
      *(f32x4*)(Ap + (size_t)tc * ROWS + e * H_DIM + h4) = acc[e];
  } else {
    // --- B[e,h] = sum_f W[e,h,f].  One wave per row, NT streamed. ---
    int row  = ((bid - A_BLOCKS) << 2) | (tid >> 6);
    int lane = tid & 63;
    const f32x4* rp = (const f32x4*)(W + (size_t)row * F_DIM);
    float s = 0.f;
    #pragma unroll
    for (int i = 0; i < 16; ++i) {
      f32x4 v = __builtin_nontemporal_load(rp + lane + (i << 6));
      s += (v.x + v.y) + (v.z + v.w);
    }
    #pragma unroll
    for (int off = 32; off > 0; off >>= 1)
      s += __shfl_down(s, off, 64);
    if (lane == 0) Bsum[row] = s;
  }

  // ---- arrival: last block computes the dot ----
  __threadfence();                 // release our stores device-wide
  __syncthreads();
  if (tid == 0) {
    int prev = atomicAdd(counter, 1);
    is_last = (prev == TOTAL_BLOCKS - 1) ? 1 : 0;
  }
  __syncthreads();
  if (!is_last) return;
  __threadfence();                 // acquire: invalidate stale cache lines

  const f32x4* B4 = (const f32x4*)Bsum;
  const f32x4* A4 = (const f32x4*)Ap;
  float s = 0.f;
  #pragma unroll
  for (int i0 = 0; i0 < ROWS / 4; i0 += 256) {
    int i = i0 + tid;
    f32x4 a = (A4[i] + A4[4096 + i]) + (A4[8192 + i] + A4[12288 + i]);
    f32x4 b = B4[i];
    s += (a.x * b.x + a.y * b.y) + (a.z * b.z + a.w * b.w);
  }
  #pragma unroll
  for (int off = 32; off > 0; off >>= 1)
    s += __shfl_down(s, off, 64);
  if ((tid & 63) == 0) red[tid >> 6] = s;
  __syncthreads();
  if (tid == 0) out[0] = (red[0] + red[1]) + (red[2] + red[3]);
}

extern "C" void kernel_launch(void* const* d_in, const int* in_sizes, int n_in,
                              void* d_out, int out_size, void* d_ws, size_t ws_size,
                              hipStream_t stream) {
  const float* hidden = (const float*)d_in[0];  // [1,1,T,H] fp32
  const float* W      = (const float*)d_in[1];  // [1,E,H,2*INTER] fp32
  const float* mask   = (const float*)d_in[2];  // [1,E,T,1] fp32
  float* out = (float*)d_out;                   // scalar
  float* ws  = (float*)d_ws;

  // zero the arrival counter (capturable async memset node)
  hipMemsetAsync((char*)d_ws + (size_t)CTR_OFF * 4, 0, 4, stream);
  fused_all<<<TOTAL_BLOCKS, 256, 0, stream>>>(hidden, W, mask, ws, out);
}

// Round 4
// 469.383 us; speedup vs baseline: 2.5589x; 2.5589x over previous
//
#include <hip/hip_runtime.h>

// Problem constants (from reference)
#define H_DIM 2048
#define E_DIM 8
#define T_DIM 2048
#define F_DIM 4096                    // INTER*2
#define ROWS (E_DIM * H_DIM)          // 16384 (e,h) rows of W
#define TCHUNK 512
#define TCHUNKS 4
#define A_BLOCKS 8                    // 2 h-blocks (1024 h) x 4 t-chunks, FIRST
#define RS_BLOCKS (ROWS / 4)          // 4096 rowsum blocks, 1 wave/row

typedef float f32x4 __attribute__((ext_vector_type(4)));

// ws layout (floats): [0,ROWS)=Bsum   [ROWS, ROWS+TCHUNKS*ROWS)=Ap partials

__global__ __launch_bounds__(256) void fused_compute(
    const float* __restrict__ hidden,   // [T, H]
    const float* __restrict__ W,        // [E, H, F]
    const float* __restrict__ mask,     // [E, T]
    float* __restrict__ ws,
    float* __restrict__ out) {
  float* Bsum = ws;
  float* Ap   = ws + ROWS;
  int bid = blockIdx.x;
  int tid = threadIdx.x;

  if (bid < A_BLOCKS) {
    // --- A[e,h] partials: Ap[tc][e,h] = sum_{t in chunk} mask[e,t]*hidden[t,h]
    if (bid == 0 && tid == 0) out[0] = 0.f;   // k2 accumulates via atomicAdd

    int hb = bid & 1;                // 2 h-blocks of 1024 columns
    int tc = bid >> 1;               // 4 t-chunks of 512
    int t0 = tc * TCHUNK;
    int h4 = hb * 1024 + tid * 4;    // each thread owns 4 consecutive h

    __shared__ float m_lds[E_DIM][TCHUNK];   // 16 KB
    #pragma unroll
    for (int i = 0; i < (E_DIM * TCHUNK) / 256; ++i) {   // 16 iters
      int idx = i * 256 + tid;
      int e = idx >> 9, tt = idx & 511;
      m_lds[e][tt] = mask[e * T_DIM + t0 + tt];
    }
    __syncthreads();

    f32x4 acc[E_DIM];
    #pragma unroll
    for (int e = 0; e < E_DIM; ++e) acc[e] = (f32x4)0.f;
    #pragma unroll 2
    for (int t = 0; t < TCHUNK; ++t) {
      f32x4 hv = *(const f32x4*)(hidden + (size_t)(t0 + t) * H_DIM + h4);
      #pragma unroll
      for (int e = 0; e < E_DIM; ++e)
        acc[e] += hv * m_lds[e][t];          // wave-uniform LDS broadcast
    }
    #pragma unroll
    for (int e = 0; e < E_DIM; ++e)
      *(f32x4*)(Ap + (size_t)tc * ROWS + e * H_DIM + h4) = acc[e];
  } else {
    // --- B[e,h] = sum_f W[e,h,f].  One wave per row, NT streamed. ---
    int row  = ((bid - A_BLOCKS) << 2) | (tid >> 6);
    int lane = tid & 63;
    const f32x4* rp = (const f32x4*)(W + (size_t)row * F_DIM);
    float s = 0.f;
    #pragma unroll
    for (int i = 0; i < 16; ++i) {
      f32x4 v = __builtin_nontemporal_load(rp + lane + (i << 6));
      s += (v.x + v.y) + (v.z + v.w);
    }
    #pragma unroll
    for (int off = 32; off > 0; off >>= 1)
      s += __shfl_down(s, off, 64);
    if (lane == 0) Bsum[row] = s;
  }
}

// 4 blocks x 1024 threads; thread i handles one f32x4 row-group.
__global__ __launch_bounds__(1024) void dot_kernel(const float* __restrict__ ws,
                                                   float* __restrict__ out) {
  const f32x4* B4 = (const f32x4*)ws;
  const f32x4* A4 = (const f32x4*)(ws + ROWS);
  int i = blockIdx.x * 1024 + threadIdx.x;    // 0 .. ROWS/4-1

  f32x4 a = (A4[i] + A4[4096 + i]) + (A4[8192 + i] + A4[12288 + i]);
  f32x4 b = B4[i];
  float s = (a.x * b.x + a.y * b.y) + (a.z * b.z + a.w * b.w);

  #pragma unroll
  for (int off = 32; off > 0; off >>= 1)
    s += __shfl_down(s, off, 64);

  __shared__ float red[16];
  int wave = threadIdx.x >> 6;
  int lane = threadIdx.x & 63;
  if (lane == 0) red[wave] = s;
  __syncthreads();
  if (threadIdx.x == 0) {
    float r = 0.f;
    #pragma unroll
    for (int w = 0; w < 16; ++w) r += red[w];
    atomicAdd(out, r);
  }
}

extern "C" void kernel_launch(void* const* d_in, const int* in_sizes, int n_in,
                              void* d_out, int out_size, void* d_ws, size_t ws_size,
                              hipStream_t stream) {
  const float* hidden = (const float*)d_in[0];  // [1,1,T,H] fp32
  const float* W      = (const float*)d_in[1];  // [1,E,H,2*INTER] fp32
  const float* mask   = (const float*)d_in[2];  // [1,E,T,1] fp32
  float* out = (float*)d_out;                   // scalar
  float* ws  = (float*)d_ws;

  fused_compute<<<A_BLOCKS + RS_BLOCKS, 256, 0, stream>>>(hidden, W, mask, ws, out);
  dot_kernel<<<4, 1024, 0, stream>>>(ws, out);
}

// Round 5
// 388.604 us; speedup vs baseline: 3.0908x; 1.2079x over previous
//
#include <hip/hip_runtime.h>

// Problem constants (from reference)
#define H_DIM 2048
#define E_DIM 8
#define T_DIM 2048
#define F_DIM 4096                    // INTER*2
#define ROWS (E_DIM * H_DIM)          // 16384 (e,h) rows of W
#define TCHUNK 128
#define TCHUNKS 16
#define A_BLOCKS 32                   // 2 h-blocks (1024 h) x 16 t-chunks, FIRST
#define RS_BLOCKS 1024                // long-lived: 4 waves/block, 4 rows/wave
#define RS_WAVES (RS_BLOCKS * 4)      // 4096 waves
#define ROWS_PER_WAVE (ROWS / RS_WAVES)   // 4

typedef float f32x4 __attribute__((ext_vector_type(4)));

// ws layout (floats): [0,ROWS)=Bsum   [ROWS, ROWS+TCHUNKS*ROWS)=Ap partials (1 MB)

__global__ __launch_bounds__(256) void fused_compute(
    const float* __restrict__ hidden,   // [T, H]
    const float* __restrict__ W,        // [E, H, F]
    const float* __restrict__ mask,     // [E, T]
    float* __restrict__ ws,
    float* __restrict__ out) {
  float* Bsum = ws;
  float* Ap   = ws + ROWS;
  int bid = blockIdx.x;
  int tid = threadIdx.x;

  if (bid < A_BLOCKS) {
    // --- A[e,h] partials: Ap[tc][e,h] = sum_{t in chunk} mask[e,t]*hidden[t,h]
    if (bid == 0 && tid == 0) out[0] = 0.f;   // dot kernel accumulates via atomicAdd

    int hb = bid & 1;                // 2 h-blocks of 1024 columns
    int tc = bid >> 1;               // 16 t-chunks of 128
    int t0 = tc * TCHUNK;
    int h4 = hb * 1024 + tid * 4;    // each thread owns 4 consecutive h

    __shared__ float m_lds[E_DIM][TCHUNK];   // 4 KB
    #pragma unroll
    for (int i = 0; i < (E_DIM * TCHUNK) / 256; ++i) {   // 4 iters
      int idx = i * 256 + tid;
      int e = idx >> 7, tt = idx & 127;
      m_lds[e][tt] = mask[e * T_DIM + t0 + tt];
    }
    __syncthreads();

    f32x4 acc[E_DIM];
    #pragma unroll
    for (int e = 0; e < E_DIM; ++e) acc[e] = (f32x4)0.f;
    #pragma unroll 2
    for (int t = 0; t < TCHUNK; ++t) {
      f32x4 hv = *(const f32x4*)(hidden + (size_t)(t0 + t) * H_DIM + h4);
      #pragma unroll
      for (int e = 0; e < E_DIM; ++e)
        acc[e] += hv * m_lds[e][t];          // wave-uniform LDS broadcast
    }
    #pragma unroll
    for (int e = 0; e < E_DIM; ++e)
      *(f32x4*)(Ap + (size_t)tc * ROWS + e * H_DIM + h4) = acc[e];
  } else {
    // --- B[row] = sum_f W[row,f]. Long-lived waves: 4 rows/wave, grid-stride.
    int wv   = ((bid - A_BLOCKS) << 2) | (tid >> 6);   // 0..4095
    int lane = tid & 63;
    float s[ROWS_PER_WAVE];
    #pragma unroll
    for (int rr = 0; rr < ROWS_PER_WAVE; ++rr) {
      int row = wv + rr * RS_WAVES;
      const f32x4* rp = (const f32x4*)(W + (size_t)row * F_DIM);
      f32x4 a = (f32x4)0.f;
      #pragma unroll
      for (int i = 0; i < 16; ++i)      // 16 x 1KB coalesced, all independent
        a += rp[lane + (i << 6)];
      s[rr] = (a.x + a.y) + (a.z + a.w);
    }
    // 4 independent shuffle-reduce chains (ILP hides bpermute latency)
    #pragma unroll
    for (int off = 32; off > 0; off >>= 1) {
      #pragma unroll
      for (int rr = 0; rr < ROWS_PER_WAVE; ++rr)
        s[rr] += __shfl_down(s[rr], off, 64);
    }
    if (lane == 0) {
      #pragma unroll
      for (int rr = 0; rr < ROWS_PER_WAVE; ++rr)
        Bsum[wv + rr * RS_WAVES] = s[rr];
    }
  }
}

// 4 blocks x 1024 threads; thread i handles one f32x4 row-group.
__global__ __launch_bounds__(1024) void dot_kernel(const float* __restrict__ ws,
                                                   float* __restrict__ out) {
  const f32x4* B4 = (const f32x4*)ws;
  const f32x4* A4 = (const f32x4*)(ws + ROWS);
  int i = blockIdx.x * 1024 + threadIdx.x;    // 0 .. ROWS/4-1

  f32x4 a = (f32x4)0.f;
  #pragma unroll
  for (int c = 0; c < TCHUNKS; ++c)
    a += A4[(size_t)c * (ROWS / 4) + i];
  f32x4 b = B4[i];
  float s = (a.x * b.x + a.y * b.y) + (a.z * b.z + a.w * b.w);

  #pragma unroll
  for (int off = 32; off > 0; off >>= 1)
    s += __shfl_down(s, off, 64);

  __shared__ float red[16];
  int wave = threadIdx.x >> 6;
  int lane = threadIdx.x & 63;
  if (lane == 0) red[wave] = s;
  __syncthreads();
  if (threadIdx.x == 0) {
    float r = 0.f;
    #pragma unroll
    for (int w = 0; w < 16; ++w) r += red[w];
    atomicAdd(out, r);
  }
}

extern "C" void kernel_launch(void* const* d_in, const int* in_sizes, int n_in,
                              void* d_out, int out_size, void* d_ws, size_t ws_size,
                              hipStream_t stream) {
  const float* hidden = (const float*)d_in[0];  // [1,1,T,H] fp32
  const float* W      = (const float*)d_in[1];  // [1,E,H,2*INTER] fp32
  const float* mask   = (const float*)d_in[2];  // [1,E,T,1] fp32
  float* out = (float*)d_out;                   // scalar
  float* ws  = (float*)d_ws;

  fused_compute<<<A_BLOCKS + RS_BLOCKS, 256, 0, stream>>>(hidden, W, mask, ws, out);
  dot_kernel<<<4, 1024, 0, stream>>>(ws, out);
}